// Round 6
// baseline (86.313 us; speedup 1.0000x reference)
//
#include <hip/hip_runtime.h>
#include <math.h>

#define BB  8
#define NN  262144
#define GG  64
#define NBG 512            // B*G
#define TOT 2097152        // B*N
#define NBLK 4096          // k_group/k_loss blocks: 256 thr x 2 pts = 512 pts/block

// ws float layout:
//   [0    .. 1024) zsumP  x2 copies (copy c at [c*512+e])
//   [1024 .. 2048) zsumT  x2
//   [2048 .. 3072) cnt    x2
//   [3072 .. 4096) interleaved (invP,invT) pairs
//   [4096]         nvalid
//   [4352 .. 4352+6*4096) per-block partials, transposed: partials[k*NBLK+blk]
#define ZP_F   0
#define ZT_F   1024
#define CNT_F  2048
#define PAIR_F 3072
#define NV_F   4096
#define PART_F 4352
#define WS_ZERO_BYTES (3072 * 4)

#define LN2   0.6931471805599453f
#define LOG2E 1.4426950408889634f

// HW transcendentals via amdgcn builtins (avoid glibc __exp2f/__log2f name clash)
__device__ __forceinline__ float fexp2(float x) { return __builtin_amdgcn_exp2f(x); }  // 2^x
__device__ __forceinline__ float flog2(float x) { return __builtin_amdgcn_logf(x); }   // log2(x)
__device__ __forceinline__ float flog1p(float x) { return flog2(1.0f + x) * LN2; }

__device__ __forceinline__ float wredf(float v) {
#pragma unroll
    for (int o = 32; o > 0; o >>= 1) v += __shfl_down(v, o, 64);
    return v;
}

// ---- Kernel 1: per-(b,g) z sums + counts. 4096 blocks x 256 thr, 2 pts/thr
__global__ __launch_bounds__(256) void k_group(const float* __restrict__ pp,
                                               const float* __restrict__ tp,
                                               const int* __restrict__ mask,
                                               const int* __restrict__ grp,
                                               float* __restrict__ ws) {
    __shared__ float sP[GG], sT[GG], sC[GG];
    if (threadIdx.x < GG) { sP[threadIdx.x] = 0.f; sT[threadIdx.x] = 0.f; sC[threadIdx.x] = 0.f; }
    __syncthreads();

    const int t = blockIdx.x * 256 + threadIdx.x;
    const int p0 = t << 1;                        // 512 pts/block; 512 blocks/batch
    const int b = p0 >> 18;

    const int2 M  = *(const int2*)(mask + p0);
    const int2 Gp = *(const int2*)(grp + p0);
    const float zP0 = pp[3 * p0 + 2], zP1 = pp[3 * p0 + 5];
    const float zT0 = tp[3 * p0 + 2], zT1 = tp[3 * p0 + 5];

    if (M.x) { atomicAdd(&sP[Gp.x], zP0); atomicAdd(&sT[Gp.x], zT0); atomicAdd(&sC[Gp.x], 1.f); }
    if (M.y) { atomicAdd(&sP[Gp.y], zP1); atomicAdd(&sT[Gp.y], zT1); atomicAdd(&sC[Gp.y], 1.f); }
    __syncthreads();
    if (threadIdx.x < GG) {
        float c = sC[threadIdx.x];
        if (c != 0.0f) {
            int e = (blockIdx.x & 1) * NBG + b * GG + threadIdx.x;   // 2-way table split
            atomicAdd(&ws[ZP_F + e], sP[threadIdx.x]);
            atomicAdd(&ws[ZT_F + e], sT[threadIdx.x]);
            atomicAdd(&ws[CNT_F + e], c);
        }
    }
}

// ---- Kernel 2: fold table copies, finalize interleaved inverse safe means + nvalid
__global__ __launch_bounds__(512) void k_groups_final(float* __restrict__ ws) {
    __shared__ float red[NBG];
    int j = threadIdx.x;
    float c  = ws[CNT_F + j] + ws[CNT_F + NBG + j];
    float sp = ws[ZP_F + j]  + ws[ZP_F + NBG + j];
    float st = ws[ZT_F + j]  + ws[ZT_F + NBG + j];
    float mP = (c > 0.f) ? (sp / fmaxf(c, 1.f)) : 1.0f;
    float mT = (c > 0.f) ? (st / fmaxf(c, 1.f)) : 1.0f;
    ws[PAIR_F + 2 * j]     = 1.0f / fmaxf(fabsf(mP), 1e-6f);
    ws[PAIR_F + 2 * j + 1] = 1.0f / fmaxf(fabsf(mT), 1e-6f);
    red[j] = c;
    __syncthreads();
    for (int s = 256; s > 0; s >>= 1) {
        if (j < s) red[j] += red[j + s];
        __syncthreads();
    }
    if (j == 0) ws[NV_F] = red[0];
}

// ---- Kernel 3: main loss pass. 4096 blocks x 256 thr, 2 pts/thr
__global__ __launch_bounds__(256) void k_loss(const float* __restrict__ pp,
                                              const float* __restrict__ tp,
                                              const float* __restrict__ p2,
                                              const float* __restrict__ t2,
                                              const float* __restrict__ pv,
                                              const float* __restrict__ tv,
                                              const float* __restrict__ pd,
                                              const float* __restrict__ td,
                                              const float* __restrict__ pn,
                                              const float* __restrict__ tn,
                                              const float* __restrict__ cf,
                                              const int* __restrict__ mask,
                                              const int* __restrict__ grp,
                                              float* __restrict__ ws) {
    const float* pairs = ws + PAIR_F;

    const int t = blockIdx.x * 256 + threadIdx.x;
    const int p0 = t << 1;
    const int bb6 = (p0 >> 18) << 6;

    const int2 M  = *(const int2*)(mask + p0);
    const int2 Gp = *(const int2*)(grp + p0);
    const float w0 = (float)M.x, w1 = (float)M.y;
    const float2 pr0 = *(const float2*)(pairs + 2 * (bb6 | Gp.x));
    const float2 pr1 = *(const float2*)(pairs + 2 * (bb6 | Gp.y));

    float s3d, s2, sv, sd, sn, sc;

    // --- L_3D
    {
        const float2* A  = (const float2*)(pp + 3 * p0);
        const float2* Bv = (const float2*)(tp + 3 * p0);
        float P[6], T[6];
        *(float2*)&P[0] = A[0];  *(float2*)&P[2] = A[1];  *(float2*)&P[4] = A[2];
        *(float2*)&T[0] = Bv[0]; *(float2*)&T[2] = Bv[1]; *(float2*)&T[4] = Bv[2];
        float a0 = 0.f, a1 = 0.f;
#pragma unroll
        for (int c = 0; c < 3; c++) {
            float a = P[c] * pr0.x,     b = T[c] * pr0.y;
            a0 += fabsf(copysignf(flog1p(fabsf(a)), a) - copysignf(flog1p(fabsf(b)), b));
            float a2 = P[3 + c] * pr1.x, b2 = T[3 + c] * pr1.y;
            a1 += fabsf(copysignf(flog1p(fabsf(a2)), a2) - copysignf(flog1p(fabsf(b2)), b2));
        }
        s3d = w0 * a0 + w1 * a1;
    }
    // --- L_2D
    {
        float4 A  = *(const float4*)(p2 + 2 * p0);
        float4 Bv = *(const float4*)(t2 + 2 * p0);
        s2 = w0 * (fabsf(A.x - Bv.x) + fabsf(A.y - Bv.y))
           + w1 * (fabsf(A.z - Bv.z) + fabsf(A.w - Bv.w));
    }
    // --- L_vis (BCE with logits), L_conf
    {
        float2 X  = *(const float2*)(pv + p0);
        float2 Tg = *(const float2*)(tv + p0);
        float2 C  = *(const float2*)(cf + p0);
        float soft0 = flog2(1.0f + fexp2(-fabsf(X.x) * LOG2E)) * LN2;
        float soft1 = flog2(1.0f + fexp2(-fabsf(X.y) * LOG2E)) * LN2;
        sv = w0 * (fmaxf(X.x, 0.f) - X.x * Tg.x + soft0)
           + w1 * (fmaxf(X.y, 0.f) - X.y * Tg.y + soft1);
        sc = w0 * C.x + w1 * C.y;
    }
    // --- L_disp
    {
        const float2* A  = (const float2*)(pd + 3 * p0);
        const float2* Bv = (const float2*)(td + 3 * p0);
        float P[6], T[6];
        *(float2*)&P[0] = A[0];  *(float2*)&P[2] = A[1];  *(float2*)&P[4] = A[2];
        *(float2*)&T[0] = Bv[0]; *(float2*)&T[2] = Bv[1]; *(float2*)&T[4] = Bv[2];
        sd = w0 * (fabsf(P[0] - T[0]) + fabsf(P[1] - T[1]) + fabsf(P[2] - T[2]))
           + w1 * (fabsf(P[3] - T[3]) + fabsf(P[4] - T[4]) + fabsf(P[5] - T[5]));
    }
    // --- L_normal
    {
        const float2* A  = (const float2*)(pn + 3 * p0);
        const float2* Bv = (const float2*)(tn + 3 * p0);
        float P[6], T[6];
        *(float2*)&P[0] = A[0];  *(float2*)&P[2] = A[1];  *(float2*)&P[4] = A[2];
        *(float2*)&T[0] = Bv[0]; *(float2*)&T[2] = Bv[1]; *(float2*)&T[4] = Bv[2];
        sn = 0.f;
#pragma unroll
        for (int k = 0; k < 2; k++) {
            float ax = P[3 * k], ay = P[3 * k + 1], az = P[3 * k + 2];
            float bx = T[3 * k], by = T[3 * k + 1], bz = T[3 * k + 2];
            float na = fmaf(ax, ax, fmaf(ay, ay, az * az));
            float nb = fmaf(bx, bx, fmaf(by, by, bz * bz));
            float dot = fmaf(ax, bx, fmaf(ay, by, az * bz));
            float r = __frsqrt_rn(fmaxf(na, 1e-24f)) * __frsqrt_rn(fmaxf(nb, 1e-24f));
            sn += (k ? w1 : w0) * (1.0f - dot * r);
        }
    }

    // block reduction -> one non-atomic write per (block, term)
    __shared__ float sred[4][6];
    float vals[6] = {s3d, s2, sv, sd, sn, sc};
    int wid = threadIdx.x >> 6, lane = threadIdx.x & 63;
#pragma unroll
    for (int k = 0; k < 6; k++) {
        float r = wredf(vals[k]);
        if (lane == 0) sred[wid][k] = r;
    }
    __syncthreads();
    if (threadIdx.x < 6) {
        float tt = sred[0][threadIdx.x] + sred[1][threadIdx.x]
                 + sred[2][threadIdx.x] + sred[3][threadIdx.x];
        ws[PART_F + threadIdx.x * NBLK + blockIdx.x] = tt;
    }
}

// ---- Kernel 4: final reduce (4096 partials x 6) + combine. 1 block x 256 thr
__global__ __launch_bounds__(256) void k_final(const float* __restrict__ ws,
                                               float* __restrict__ out) {
    const float* part = ws + PART_F;
    double loc[6] = {0, 0, 0, 0, 0, 0};
    for (int j = threadIdx.x; j < NBLK; j += 256) {
#pragma unroll
        for (int k = 0; k < 6; k++) loc[k] += (double)part[k * NBLK + j];
    }
    __shared__ double dred[4][6];
    int wid = threadIdx.x >> 6, lane = threadIdx.x & 63;
#pragma unroll
    for (int k = 0; k < 6; k++) {
        double v = loc[k];
#pragma unroll
        for (int o = 32; o > 0; o >>= 1) v += __shfl_down(v, o, 64);
        if (lane == 0) dred[wid][k] = v;
    }
    __syncthreads();
    if (threadIdx.x == 0) {
        double a[6];
#pragma unroll
        for (int k = 0; k < 6; k++)
            a[k] = dred[0][k] + dred[1][k] + dred[2][k] + dred[3][k];
        double nv = (double)ws[NV_F];
        double d1 = nv + 1e-6;
        double d3 = 3.0 * nv + 1e-6;
        double l3d   = a[0] / d3;
        double l2d   = a[1] / (2.0 * nv + 1e-6);
        double lvis  = a[2] / d1;
        double ldisp = a[3] / d3;   // disp is (B,N,3): mask broadcasts to 3 channels
        double lnorm = a[4] / d1;
        double lconf = a[5] / d1;
        out[0] = (float)(l3d + 0.1 * (l2d + lvis + ldisp) + 0.5 * lnorm + 0.2 * lconf);
    }
}

extern "C" void kernel_launch(void* const* d_in, const int* in_sizes, int n_in,
                              void* d_out, int out_size, void* d_ws, size_t ws_size,
                              hipStream_t stream) {
    const float* pp = (const float*)d_in[0];
    const float* tp = (const float*)d_in[1];
    const float* p2 = (const float*)d_in[2];
    const float* t2 = (const float*)d_in[3];
    const float* pv = (const float*)d_in[4];
    const float* tv = (const float*)d_in[5];
    const float* pd = (const float*)d_in[6];
    const float* td = (const float*)d_in[7];
    const float* pn = (const float*)d_in[8];
    const float* tn = (const float*)d_in[9];
    const float* cf = (const float*)d_in[10];
    const int* mask = (const int*)d_in[11];
    const int* grp  = (const int*)d_in[12];
    float* ws = (float*)d_ws;
    float* out = (float*)d_out;

    (void)hipMemsetAsync(d_ws, 0, WS_ZERO_BYTES, stream);
    k_group<<<NBLK, 256, 0, stream>>>(pp, tp, mask, grp, ws);
    k_groups_final<<<1, NBG, 0, stream>>>(ws);
    k_loss<<<NBLK, 256, 0, stream>>>(pp, tp, p2, t2, pv, tv, pd, td, pn, tn, cf, mask, grp, ws);
    k_final<<<1, 256, 0, stream>>>(ws, out);
}

// Round 7
// 80.994 us; speedup vs baseline: 1.0657x; 1.0657x over previous
//
#include <hip/hip_runtime.h>
#include <math.h>

#define GG   64
#define NBG  512           // B*G
#define TOT  2097152       // B*N
#define PTS  1024          // points per block (256 thr x 4)
#define NBLK (TOT / PTS)   // 2048

// ws float layout:
//   [0    ..  512) zsumP
//   [512  .. 1024) zsumT
//   [1024 .. 1536) cnt
//   [1536 .. 2560) interleaved (invP,invT) pairs
//   [2560]         nvalid
//   [2816 .. 2816+6*2048) per-block partials, transposed
#define ZP_F   0
#define ZT_F   512
#define CNT_F  1024
#define PAIR_F 1536
#define NV_F   2560
#define PART_F 2816
#define WS_ZERO_BYTES (1536 * 4)

#define LN2   0.6931471805599453f
#define LOG2E 1.4426950408889634f

__device__ __forceinline__ float fexp2(float x) { return __builtin_amdgcn_exp2f(x); }
__device__ __forceinline__ float flog2(float x) { return __builtin_amdgcn_logf(x); }
__device__ __forceinline__ float flog1p(float x) { return flog2(1.0f + x) * LN2; }

__device__ __forceinline__ float wredf(float v) {
#pragma unroll
    for (int o = 32; o > 0; o >>= 1) v += __shfl_down(v, o, 64);
    return v;
}

// ---- Kernel 1: per-(b,g) z sums + counts. LDS-staged coalesced reads.
__global__ __launch_bounds__(256) void k_group(const float* __restrict__ pp,
                                               const float* __restrict__ tp,
                                               const int* __restrict__ mask,
                                               const int* __restrict__ grp,
                                               float* __restrict__ ws) {
    __shared__ float4 bufA[768], bufB[768];
    __shared__ float sP[GG], sT[GG], sC[GG];
    const int tid = threadIdx.x;
    if (tid < GG) { sP[tid] = 0.f; sT[tid] = 0.f; sC[tid] = 0.f; }

    const int base = blockIdx.x * PTS;
    const int b = base >> 18;
    const int p0 = base + 4 * tid;

    const float4* gx = (const float4*)(pp + (size_t)base * 3);
    const float4* gy = (const float4*)(tp + (size_t)base * 3);
#pragma unroll
    for (int j = 0; j < 3; j++) {
        bufA[tid + 256 * j] = gx[tid + 256 * j];
        bufB[tid + 256 * j] = gy[tid + 256 * j];
    }
    const int4 M  = *(const int4*)(mask + p0);
    const int4 Gp = *(const int4*)(grp + p0);
    __syncthreads();

    float4 a0 = bufA[3 * tid], a1 = bufA[3 * tid + 1], a2 = bufA[3 * tid + 2];
    float4 b0 = bufB[3 * tid], b1 = bufB[3 * tid + 1], b2 = bufB[3 * tid + 2];
    // z components: pt0=a0.z pt1=a1.y pt2=a2.x pt3=a2.w
    if (M.x) { atomicAdd(&sP[Gp.x], a0.z); atomicAdd(&sT[Gp.x], b0.z); atomicAdd(&sC[Gp.x], 1.f); }
    if (M.y) { atomicAdd(&sP[Gp.y], a1.y); atomicAdd(&sT[Gp.y], b1.y); atomicAdd(&sC[Gp.y], 1.f); }
    if (M.z) { atomicAdd(&sP[Gp.z], a2.x); atomicAdd(&sT[Gp.z], b2.x); atomicAdd(&sC[Gp.z], 1.f); }
    if (M.w) { atomicAdd(&sP[Gp.w], a2.w); atomicAdd(&sT[Gp.w], b2.w); atomicAdd(&sC[Gp.w], 1.f); }
    __syncthreads();

    if (tid < GG) {
        float c = sC[tid];
        if (c != 0.0f) {
            int e = b * GG + tid;
            atomicAdd(&ws[ZP_F + e], sP[tid]);
            atomicAdd(&ws[ZT_F + e], sT[tid]);
            atomicAdd(&ws[CNT_F + e], c);
        }
    }
}

// ---- Kernel 2: finalize interleaved inverse safe means + nvalid. 1 block x 512
__global__ __launch_bounds__(512) void k_groups_final(float* __restrict__ ws) {
    __shared__ float red[NBG];
    int j = threadIdx.x;
    float c  = ws[CNT_F + j];
    float mP = (c > 0.f) ? (ws[ZP_F + j] / fmaxf(c, 1.f)) : 1.0f;
    float mT = (c > 0.f) ? (ws[ZT_F + j] / fmaxf(c, 1.f)) : 1.0f;
    ws[PAIR_F + 2 * j]     = 1.0f / fmaxf(fabsf(mP), 1e-6f);
    ws[PAIR_F + 2 * j + 1] = 1.0f / fmaxf(fabsf(mT), 1e-6f);
    red[j] = c;
    __syncthreads();
    for (int s = 256; s > 0; s >>= 1) {
        if (j < s) red[j] += red[j + s];
        __syncthreads();
    }
    if (j == 0) ws[NV_F] = red[0];
}

// ---- Kernel 3: main loss. 2048 blocks x 256 thr x 4 pts. xyz arrays staged via LDS.
__global__ __launch_bounds__(256) void k_loss(const float* __restrict__ pp,
                                              const float* __restrict__ tp,
                                              const float* __restrict__ p2,
                                              const float* __restrict__ t2,
                                              const float* __restrict__ pv,
                                              const float* __restrict__ tv,
                                              const float* __restrict__ pd,
                                              const float* __restrict__ td,
                                              const float* __restrict__ pn,
                                              const float* __restrict__ tn,
                                              const float* __restrict__ cf,
                                              const int* __restrict__ mask,
                                              const int* __restrict__ grp,
                                              float* __restrict__ ws) {
    __shared__ float4 bufA[768], bufB[768];
    const int tid = threadIdx.x;
    const int base = blockIdx.x * PTS;
    const int p0 = base + 4 * tid;
    const int bb6 = (base >> 18) << 6;
    const float* pairs = ws + PAIR_F;

    // ---- direct (already-coalesced) loads + their terms first, freeing registers
    const int4 M  = *(const int4*)(mask + p0);
    const int4 Gp = *(const int4*)(grp + p0);
    const float w[4] = {(float)M.x, (float)M.y, (float)M.z, (float)M.w};
    const int Gs[4] = {Gp.x, Gp.y, Gp.z, Gp.w};
    float iP[4], iT[4];
#pragma unroll
    for (int k = 0; k < 4; k++) {
        float2 pr = *(const float2*)(pairs + 2 * (bb6 | Gs[k]));
        iP[k] = pr.x; iT[k] = pr.y;
    }

    float s3d = 0.f, s2 = 0.f, sv = 0.f, sd = 0.f, sn = 0.f, sc = 0.f;

    {   // L_2D
        float4 Aa = ((const float4*)(p2 + 2 * (size_t)p0))[0];
        float4 Ab = ((const float4*)(p2 + 2 * (size_t)p0))[1];
        float4 Ba = ((const float4*)(t2 + 2 * (size_t)p0))[0];
        float4 Bb = ((const float4*)(t2 + 2 * (size_t)p0))[1];
        s2 = w[0] * (fabsf(Aa.x - Ba.x) + fabsf(Aa.y - Ba.y))
           + w[1] * (fabsf(Aa.z - Ba.z) + fabsf(Aa.w - Ba.w))
           + w[2] * (fabsf(Ab.x - Bb.x) + fabsf(Ab.y - Bb.y))
           + w[3] * (fabsf(Ab.z - Bb.z) + fabsf(Ab.w - Bb.w));
    }
    {   // L_vis + L_conf
        float4 X  = *(const float4*)(pv + p0);
        float4 Tg = *(const float4*)(tv + p0);
        float4 C  = *(const float4*)(cf + p0);
        const float xs[4] = {X.x, X.y, X.z, X.w};
        const float ts[4] = {Tg.x, Tg.y, Tg.z, Tg.w};
        const float cs[4] = {C.x, C.y, C.z, C.w};
#pragma unroll
        for (int k = 0; k < 4; k++) {
            float x = xs[k];
            float soft = flog2(1.0f + fexp2(-fabsf(x) * LOG2E)) * LN2;
            sv += w[k] * (fmaxf(x, 0.f) - x * ts[k] + soft);
            sc += w[k] * cs[k];
        }
    }

    // ---- Phase 1: pp/tp -> L_3D
    {
        const float4* gx = (const float4*)(pp + (size_t)base * 3);
        const float4* gy = (const float4*)(tp + (size_t)base * 3);
#pragma unroll
        for (int j = 0; j < 3; j++) {
            bufA[tid + 256 * j] = gx[tid + 256 * j];
            bufB[tid + 256 * j] = gy[tid + 256 * j];
        }
        __syncthreads();
        float P[12], T[12];
        *(float4*)&P[0] = bufA[3 * tid]; *(float4*)&P[4] = bufA[3 * tid + 1]; *(float4*)&P[8] = bufA[3 * tid + 2];
        *(float4*)&T[0] = bufB[3 * tid]; *(float4*)&T[4] = bufB[3 * tid + 1]; *(float4*)&T[8] = bufB[3 * tid + 2];
        __syncthreads();
#pragma unroll
        for (int k = 0; k < 4; k++) {
            float acc = 0.f;
#pragma unroll
            for (int c = 0; c < 3; c++) {
                float a = P[3 * k + c] * iP[k];
                float b = T[3 * k + c] * iT[k];
                acc += fabsf(copysignf(flog1p(fabsf(a)), a) - copysignf(flog1p(fabsf(b)), b));
            }
            s3d += w[k] * acc;
        }
    }
    // ---- Phase 2: pd/td -> L_disp
    {
        const float4* gx = (const float4*)(pd + (size_t)base * 3);
        const float4* gy = (const float4*)(td + (size_t)base * 3);
#pragma unroll
        for (int j = 0; j < 3; j++) {
            bufA[tid + 256 * j] = gx[tid + 256 * j];
            bufB[tid + 256 * j] = gy[tid + 256 * j];
        }
        __syncthreads();
        float P[12], T[12];
        *(float4*)&P[0] = bufA[3 * tid]; *(float4*)&P[4] = bufA[3 * tid + 1]; *(float4*)&P[8] = bufA[3 * tid + 2];
        *(float4*)&T[0] = bufB[3 * tid]; *(float4*)&T[4] = bufB[3 * tid + 1]; *(float4*)&T[8] = bufB[3 * tid + 2];
        __syncthreads();
#pragma unroll
        for (int k = 0; k < 4; k++) {
            float acc = fabsf(P[3 * k] - T[3 * k]) + fabsf(P[3 * k + 1] - T[3 * k + 1])
                      + fabsf(P[3 * k + 2] - T[3 * k + 2]);
            sd += w[k] * acc;
        }
    }
    // ---- Phase 3: pn/tn -> L_normal
    {
        const float4* gx = (const float4*)(pn + (size_t)base * 3);
        const float4* gy = (const float4*)(tn + (size_t)base * 3);
#pragma unroll
        for (int j = 0; j < 3; j++) {
            bufA[tid + 256 * j] = gx[tid + 256 * j];
            bufB[tid + 256 * j] = gy[tid + 256 * j];
        }
        __syncthreads();
        float P[12], T[12];
        *(float4*)&P[0] = bufA[3 * tid]; *(float4*)&P[4] = bufA[3 * tid + 1]; *(float4*)&P[8] = bufA[3 * tid + 2];
        *(float4*)&T[0] = bufB[3 * tid]; *(float4*)&T[4] = bufB[3 * tid + 1]; *(float4*)&T[8] = bufB[3 * tid + 2];
#pragma unroll
        for (int k = 0; k < 4; k++) {
            float ax = P[3 * k], ay = P[3 * k + 1], az = P[3 * k + 2];
            float bx = T[3 * k], by = T[3 * k + 1], bz = T[3 * k + 2];
            float na = fmaf(ax, ax, fmaf(ay, ay, az * az));
            float nb = fmaf(bx, bx, fmaf(by, by, bz * bz));
            float dot = fmaf(ax, bx, fmaf(ay, by, az * bz));
            float r = __frsqrt_rn(fmaxf(na, 1e-24f)) * __frsqrt_rn(fmaxf(nb, 1e-24f));
            sn += w[k] * (1.0f - dot * r);
        }
    }

    // block reduction -> one non-atomic write per (block, term)
    __shared__ float sred[4][6];
    float vals[6] = {s3d, s2, sv, sd, sn, sc};
    int wid = threadIdx.x >> 6, lane = threadIdx.x & 63;
#pragma unroll
    for (int k = 0; k < 6; k++) {
        float r = wredf(vals[k]);
        if (lane == 0) sred[wid][k] = r;
    }
    __syncthreads();
    if (threadIdx.x < 6) {
        float tt = sred[0][threadIdx.x] + sred[1][threadIdx.x]
                 + sred[2][threadIdx.x] + sred[3][threadIdx.x];
        ws[PART_F + threadIdx.x * NBLK + blockIdx.x] = tt;
    }
}

// ---- Kernel 4: final reduce (2048 partials x 6) + combine. 1 block x 256 thr
__global__ __launch_bounds__(256) void k_final(const float* __restrict__ ws,
                                               float* __restrict__ out) {
    const float* part = ws + PART_F;
    double loc[6] = {0, 0, 0, 0, 0, 0};
    for (int j = threadIdx.x; j < NBLK; j += 256) {
#pragma unroll
        for (int k = 0; k < 6; k++) loc[k] += (double)part[k * NBLK + j];
    }
    __shared__ double dred[4][6];
    int wid = threadIdx.x >> 6, lane = threadIdx.x & 63;
#pragma unroll
    for (int k = 0; k < 6; k++) {
        double v = loc[k];
#pragma unroll
        for (int o = 32; o > 0; o >>= 1) v += __shfl_down(v, o, 64);
        if (lane == 0) dred[wid][k] = v;
    }
    __syncthreads();
    if (threadIdx.x == 0) {
        double a[6];
#pragma unroll
        for (int k = 0; k < 6; k++)
            a[k] = dred[0][k] + dred[1][k] + dred[2][k] + dred[3][k];
        double nv = (double)ws[NV_F];
        double d1 = nv + 1e-6;
        double d3 = 3.0 * nv + 1e-6;
        double l3d   = a[0] / d3;
        double l2d   = a[1] / (2.0 * nv + 1e-6);
        double lvis  = a[2] / d1;
        double ldisp = a[3] / d3;   // disp is (B,N,3): mask broadcasts to 3 channels
        double lnorm = a[4] / d1;
        double lconf = a[5] / d1;
        out[0] = (float)(l3d + 0.1 * (l2d + lvis + ldisp) + 0.5 * lnorm + 0.2 * lconf);
    }
}

extern "C" void kernel_launch(void* const* d_in, const int* in_sizes, int n_in,
                              void* d_out, int out_size, void* d_ws, size_t ws_size,
                              hipStream_t stream) {
    const float* pp = (const float*)d_in[0];
    const float* tp = (const float*)d_in[1];
    const float* p2 = (const float*)d_in[2];
    const float* t2 = (const float*)d_in[3];
    const float* pv = (const float*)d_in[4];
    const float* tv = (const float*)d_in[5];
    const float* pd = (const float*)d_in[6];
    const float* td = (const float*)d_in[7];
    const float* pn = (const float*)d_in[8];
    const float* tn = (const float*)d_in[9];
    const float* cf = (const float*)d_in[10];
    const int* mask = (const int*)d_in[11];
    const int* grp  = (const int*)d_in[12];
    float* ws = (float*)d_ws;
    float* out = (float*)d_out;

    (void)hipMemsetAsync(d_ws, 0, WS_ZERO_BYTES, stream);
    k_group<<<NBLK, 256, 0, stream>>>(pp, tp, mask, grp, ws);
    k_groups_final<<<1, NBG, 0, stream>>>(ws);
    k_loss<<<NBLK, 256, 0, stream>>>(pp, tp, p2, t2, pv, tv, pd, td, pn, tn, cf, mask, grp, ws);
    k_final<<<1, 256, 0, stream>>>(ws, out);
}